// Round 2
// baseline (2348.738 us; speedup 1.0000x reference)
//
#include <hip/hip_runtime.h>

typedef __attribute__((ext_vector_type(8))) short bf16x8;
typedef __attribute__((ext_vector_type(4))) float f32x4;

#define E_N   100000
#define ND_N  50000
#define NN_N  100000

__device__ __forceinline__ float b2f(unsigned short u) {
    return __uint_as_float(((unsigned int)u) << 16);
}
__device__ __forceinline__ unsigned short f2b(float f) {
    unsigned int b = __float_as_uint(f);
    b += 0x7fffu + ((b >> 16) & 1u);
    return (unsigned short)(b >> 16);
}
__device__ __forceinline__ unsigned int mono(float f) {
    unsigned int u = __float_as_uint(f);
    return (u & 0x80000000u) ? ~u : (u | 0x80000000u);
}
__device__ __forceinline__ float unmono(unsigned int u) {
    unsigned int v = (u & 0x80000000u) ? (u & 0x7fffffffu) : ~u;
    return __uint_as_float(v);
}
__device__ __forceinline__ float frcp(float x) { return __builtin_amdgcn_rcpf(x); }
__device__ __forceinline__ float fsig(float x) { return frcp(1.f + __expf(-x)); }
__device__ __forceinline__ float ftanhf(float x) {
    float e = __expf(2.f * x);
    return 1.f - 2.f * frcp(e + 1.f);
}

// ---------------------------------------------------------------------------
// f32 -> bf16 conversion (RTN), vectorized
__global__ void conv_f2b(const float* __restrict__ src, unsigned short* __restrict__ dst, int n4) {
    int i = blockIdx.x * 256 + threadIdx.x;
    if (i < n4) {
        float4 v = ((const float4*)src)[i];
        ushort4 o;
        o.x = f2b(v.x); o.y = f2b(v.y); o.z = f2b(v.z); o.w = f2b(v.w);
        ((ushort4*)dst)[i] = o;
    }
}

__global__ void zero_u4(uint4* __restrict__ p, int n4) {
    int i = blockIdx.x * 256 + threadIdx.x;
    if (i < n4) p[i] = make_uint4(0u, 0u, 0u, 0u);
}

// ---------------------------------------------------------------------------
// One GRU step. Block = 32 edges, 512 threads (8 waves), wave w owns output
// cols [w*64, w*64+64). Computes all 3 gate GEMM chunks fused.
__global__ __launch_bounds__(512) void gru_step(
    const unsigned short* __restrict__ feat16,   // [NN, 64] bf16
    const int* __restrict__ emi,                 // [E, 3]
    const unsigned short* __restrict__ hprev,    // [E, 512] bf16 (unused t==0)
    unsigned short* __restrict__ hnext,          // [E, 512] bf16
    const unsigned short* __restrict__ wih,      // [1536, 64] bf16
    const unsigned short* __restrict__ whh,      // [1536, 512] bf16
    const float* __restrict__ bih,
    const float* __restrict__ bhh,
    int t)
{
    __shared__ __align__(16) unsigned char lds_h[32 * 1024];  // 32 x 512 bf16, swizzled
    __shared__ __align__(16) unsigned char lds_x[32 * 128];   // 32 x  64 bf16, swizzled

    const int tid = threadIdx.x;
    const int eb  = blockIdx.x * 32;

    // stage x tile (gathered features, f32 table pre-converted to bf16)
    if (tid < 256) {
        int row = tid >> 3, c = tid & 7;
        int node = emi[(eb + row) * 3 + t];
        uint4 v = *(const uint4*)(feat16 + (size_t)node * 64 + c * 8);
        *(uint4*)(lds_x + row * 128 + ((c * 16) ^ ((row & 7) << 4))) = v;
    }
    // stage h tile (coalesced), XOR-swizzled rows
    if (t > 0) {
        #pragma unroll
        for (int q = 0; q < 4; ++q) {
            int chunk = tid + q * 512;
            int row = chunk >> 6, c = chunk & 63;
            uint4 v = *(const uint4*)(hprev + (size_t)(eb + row) * 512 + c * 8);
            *(uint4*)(lds_h + row * 1024 + ((c * 16) ^ ((row & 7) << 4))) = v;
        }
    }
    __syncthreads();

    const int lane = tid & 63;
    const int wid  = tid >> 6;
    const int l15  = lane & 15;
    const int hi8  = (lane >> 4) * 8;    // k-offset of this lane's 8 elements
    const int cb   = wid * 64;

    f32x4 acc_r[2][4], acc_z[2][4], acc_in[2][4], acc_hn[2][4];
    #pragma unroll
    for (int ri = 0; ri < 2; ++ri)
        #pragma unroll
        for (int c = 0; c < 4; ++c) {
            f32x4 zz = {0.f, 0.f, 0.f, 0.f};
            acc_r[ri][c] = zz; acc_z[ri][c] = zz;
            acc_in[ri][c] = zz; acc_hn[ri][c] = zz;
        }

    // ---- x @ W_ih^T, K = 64 (2 k-chunks of 32) ----
    {
        const unsigned short* wbase = wih + (size_t)(cb + l15) * 64 + hi8;
        #pragma unroll
        for (int kk = 0; kk < 2; ++kk) {
            int kb = (kk * 32 + hi8) * 2;
            bf16x8 af[2];
            #pragma unroll
            for (int ri = 0; ri < 2; ++ri) {
                int row = ri * 16 + l15;
                af[ri] = *(const bf16x8*)(lds_x + row * 128 + (kb ^ ((row & 7) << 4)));
            }
            bf16x8 br[4], bz[4], bn[4];
            #pragma unroll
            for (int c = 0; c < 4; ++c) {
                br[c] = *(const bf16x8*)(wbase +         c * 1024 + kk * 32);
                bz[c] = *(const bf16x8*)(wbase + 32768 + c * 1024 + kk * 32);
                bn[c] = *(const bf16x8*)(wbase + 65536 + c * 1024 + kk * 32);
            }
            #pragma unroll
            for (int c = 0; c < 4; ++c)
                #pragma unroll
                for (int ri = 0; ri < 2; ++ri) {
                    acc_r[ri][c]  = __builtin_amdgcn_mfma_f32_16x16x32_bf16(af[ri], br[c], acc_r[ri][c], 0, 0, 0);
                    acc_z[ri][c]  = __builtin_amdgcn_mfma_f32_16x16x32_bf16(af[ri], bz[c], acc_z[ri][c], 0, 0, 0);
                    acc_in[ri][c] = __builtin_amdgcn_mfma_f32_16x16x32_bf16(af[ri], bn[c], acc_in[ri][c], 0, 0, 0);
                }
        }
    }

    // ---- h @ W_hh^T, K = 512 (16 k-chunks of 32) ----
    if (t > 0) {
        const unsigned short* wbase = whh + (size_t)(cb + l15) * 512 + hi8;
        #pragma unroll 1
        for (int kk = 0; kk < 16; ++kk) {
            int k0 = kk * 32;
            int kb = (k0 + hi8) * 2;
            bf16x8 af[2];
            #pragma unroll
            for (int ri = 0; ri < 2; ++ri) {
                int row = ri * 16 + l15;
                af[ri] = *(const bf16x8*)(lds_h + row * 1024 + (kb ^ ((row & 7) << 4)));
            }
            bf16x8 br[4], bz[4], bn[4];
            #pragma unroll
            for (int c = 0; c < 4; ++c) {
                br[c] = *(const bf16x8*)(wbase +          c * 8192 + k0);
                bz[c] = *(const bf16x8*)(wbase + 262144 + c * 8192 + k0);
                bn[c] = *(const bf16x8*)(wbase + 524288 + c * 8192 + k0);
            }
            #pragma unroll
            for (int c = 0; c < 4; ++c)
                #pragma unroll
                for (int ri = 0; ri < 2; ++ri) {
                    acc_r[ri][c]  = __builtin_amdgcn_mfma_f32_16x16x32_bf16(af[ri], br[c], acc_r[ri][c], 0, 0, 0);
                    acc_z[ri][c]  = __builtin_amdgcn_mfma_f32_16x16x32_bf16(af[ri], bz[c], acc_z[ri][c], 0, 0, 0);
                    acc_hn[ri][c] = __builtin_amdgcn_mfma_f32_16x16x32_bf16(af[ri], bn[c], acc_hn[ri][c], 0, 0, 0);
                }
        }
    }

    // ---- gate math + store h_next (bf16) ----
    #pragma unroll
    for (int c = 0; c < 4; ++c) {
        int col = cb + c * 16 + l15;
        float brz0 = bih[col] + bhh[col];
        float brz1 = bih[512 + col] + bhh[512 + col];
        float bin_ = bih[1024 + col];
        float bhn_ = bhh[1024 + col];
        #pragma unroll
        for (int ri = 0; ri < 2; ++ri) {
            int rb = ri * 16 + (lane >> 4) * 4;
            #pragma unroll
            for (int j = 0; j < 4; ++j) {
                float r = fsig(acc_r[ri][c][j] + brz0);
                float z = fsig(acc_z[ri][c][j] + brz1);
                float n = ftanhf(acc_in[ri][c][j] + bin_ + r * (acc_hn[ri][c][j] + bhn_));
                float hold = 0.f;
                if (t > 0) {
                    int rl = rb + j;
                    hold = b2f(*(const unsigned short*)(lds_h + rl * 1024 + ((col * 2) ^ ((rl & 7) << 4))));
                }
                float hv = (1.f - z) * n + z * hold;
                hnext[(size_t)(eb + rb + j) * 512 + col] = f2b(hv);
            }
        }
    }
}

// ---------------------------------------------------------------------------
// attention logits + leaky relu + segment max (monotone-uint atomicMax).
// One wave per edge; 8-lane groups own one head each.
__global__ __launch_bounds__(256) void attn_logits(
    const unsigned short* __restrict__ hl, const float* __restrict__ attnw,
    const int* __restrict__ dstp, float* __restrict__ a, unsigned int* __restrict__ amax)
{
    int e = blockIdx.x * 4 + (threadIdx.x >> 6);
    int lane = threadIdx.x & 63;
    uint4 v = *(const uint4*)(hl + (size_t)e * 512 + lane * 8);
    int h = lane >> 3;
    int dp = (lane & 7) * 8;
    float4 w0 = *(const float4*)(attnw + h * 64 + dp);
    float4 w1 = *(const float4*)(attnw + h * 64 + dp + 4);
    const unsigned short* u = (const unsigned short*)&v;
    float s = b2f(u[0]) * w0.x + b2f(u[1]) * w0.y + b2f(u[2]) * w0.z + b2f(u[3]) * w0.w
            + b2f(u[4]) * w1.x + b2f(u[5]) * w1.y + b2f(u[6]) * w1.z + b2f(u[7]) * w1.w;
    s += __shfl_xor(s, 1);
    s += __shfl_xor(s, 2);
    s += __shfl_xor(s, 4);
    if ((lane & 7) == 0) {
        float av = s > 0.f ? s : 0.01f * s;
        a[e * 8 + h] = av;
        atomicMax(&amax[dstp[e] * 8 + h], mono(av));
    }
}

// exp(a - max) in place + segment sum
__global__ __launch_bounds__(256) void attn_exp(
    const int* __restrict__ dstp, float* __restrict__ a,
    const unsigned int* __restrict__ amax, float* __restrict__ asum)
{
    int i = blockIdx.x * 256 + threadIdx.x;   // E*8 exact
    int e = i >> 3, h = i & 7;
    int d = dstp[e];
    float m = unmono(amax[d * 8 + h]);
    float p = __expf(a[i] - m);
    a[i] = p;
    atomicAdd(&asum[d * 8 + h], p);
}

// alpha-weighted scatter of eft into output
__global__ __launch_bounds__(256) void scatter_out(
    const unsigned short* __restrict__ hl, const int* __restrict__ dstp,
    const float* __restrict__ a, const float* __restrict__ asum,
    float* __restrict__ out)
{
    int i = blockIdx.x * 256 + threadIdx.x;   // E*128 exact
    int e = i >> 7;
    int q = i & 127;
    int c0 = q * 4, h = q >> 4;
    int d = dstp[e];
    float alpha = a[e * 8 + h] * frcp(asum[d * 8 + h]);
    uint2 v = *(const uint2*)(hl + (size_t)e * 512 + c0);
    float* op = out + (size_t)d * 512 + c0;
    atomicAdd(op + 0, b2f((unsigned short)(v.x & 0xffffu)) * alpha);
    atomicAdd(op + 1, b2f((unsigned short)(v.x >> 16)) * alpha);
    atomicAdd(op + 2, b2f((unsigned short)(v.y & 0xffffu)) * alpha);
    atomicAdd(op + 3, b2f((unsigned short)(v.y >> 16)) * alpha);
}

// ---------------------------------------------------------------------------
extern "C" void kernel_launch(void* const* d_in, const int* in_sizes, int n_in,
                              void* d_out, int out_size, void* d_ws, size_t ws_size,
                              hipStream_t stream)
{
    const float* features = (const float*)d_in[0];
    const float* W_ih     = (const float*)d_in[1];
    const float* W_hh     = (const float*)d_in[2];
    const float* b_ih     = (const float*)d_in[3];
    const float* b_hh     = (const float*)d_in[4];
    const float* attnw    = (const float*)d_in[5];
    const int*   emi      = (const int*)d_in[6];
    const int*   dstp     = (const int*)d_in[7];

    char* ws = (char*)d_ws;
    size_t off = 0;
    auto alloc = [&](size_t bytes) -> void* {
        void* p = ws + off;
        off = (off + bytes + 255) & ~(size_t)255;
        return p;
    };
    unsigned short* feat16 = (unsigned short*)alloc((size_t)NN_N * 64 * 2);   // 12.8 MB
    unsigned short* wih16  = (unsigned short*)alloc((size_t)1536 * 64 * 2);
    unsigned short* whh16  = (unsigned short*)alloc((size_t)1536 * 512 * 2);
    unsigned short* h0     = (unsigned short*)alloc((size_t)E_N * 512 * 2);   // 102.4 MB
    unsigned short* h1     = (unsigned short*)alloc((size_t)E_N * 512 * 2);   // 102.4 MB
    float*          abuf   = (float*)alloc((size_t)E_N * 8 * 4);
    unsigned int*   amax   = (unsigned int*)alloc((size_t)ND_N * 8 * 4);      // contiguous with asum
    float*          asum   = (float*)alloc((size_t)ND_N * 8 * 4);

    // dtype conversions (every call — ws is re-poisoned)
    conv_f2b<<<(NN_N * 64 / 4 + 255) / 256, 256, 0, stream>>>(features, feat16, NN_N * 64 / 4);
    conv_f2b<<<(1536 * 64 / 4 + 255) / 256, 256, 0, stream>>>(W_ih, wih16, 1536 * 64 / 4);
    conv_f2b<<<(1536 * 512 / 4 + 255) / 256, 256, 0, stream>>>(W_hh, whh16, 1536 * 512 / 4);

    // zero: output (25.6M f32) and amax+asum (contiguous 3.2 MB)
    zero_u4<<<(out_size / 4 + 255) / 256, 256, 0, stream>>>((uint4*)d_out, out_size / 4);
    zero_u4<<<(ND_N * 8 * 2 / 4 + 255) / 256, 256, 0, stream>>>((uint4*)amax, ND_N * 8 * 2 / 4);

    // GRU: 3 steps, ping-pong h buffers; h_last ends in h0
    gru_step<<<E_N / 32, 512, 0, stream>>>(feat16, emi, nullptr, h0, wih16, whh16, b_ih, b_hh, 0);
    gru_step<<<E_N / 32, 512, 0, stream>>>(feat16, emi, h0, h1, wih16, whh16, b_ih, b_hh, 1);
    gru_step<<<E_N / 32, 512, 0, stream>>>(feat16, emi, h1, h0, wih16, whh16, b_ih, b_hh, 2);

    // attention + edge softmax + scatter
    attn_logits<<<E_N / 4, 256, 0, stream>>>(h0, attnw, dstp, abuf, amax);
    attn_exp<<<E_N * 8 / 256, 256, 0, stream>>>(dstp, abuf, amax, asum);
    scatter_out<<<E_N * 128 / 256, 256, 0, stream>>>(h0, dstp, abuf, asum, (float*)d_out);
}

// Round 6
// 1450.279 us; speedup vs baseline: 1.6195x; 1.6195x over previous
//
#include <hip/hip_runtime.h>

typedef __attribute__((ext_vector_type(8))) short bf16x8;
typedef __attribute__((ext_vector_type(4))) float f32x4;

#define E_N   100000
#define ND_N  50000
#define NN_N  100000

__device__ __forceinline__ float b2f(unsigned short u) {
    return __uint_as_float(((unsigned int)u) << 16);
}
__device__ __forceinline__ unsigned short f2b(float f) {
    unsigned int b = __float_as_uint(f);
    b += 0x7fffu + ((b >> 16) & 1u);
    return (unsigned short)(b >> 16);
}
__device__ __forceinline__ unsigned int mono(float f) {
    unsigned int u = __float_as_uint(f);
    return (u & 0x80000000u) ? ~u : (u | 0x80000000u);
}
__device__ __forceinline__ float unmono(unsigned int u) {
    unsigned int v = (u & 0x80000000u) ? (u & 0x7fffffffu) : ~u;
    return __uint_as_float(v);
}
__device__ __forceinline__ float frcp(float x) { return __builtin_amdgcn_rcpf(x); }
__device__ __forceinline__ float fsig(float x) { return frcp(1.f + __expf(-x)); }
__device__ __forceinline__ float ftanhf(float x) {
    float e = __expf(2.f * x);
    return 1.f - 2.f * frcp(e + 1.f);
}

// async global->LDS, 16B per lane. LDS dest must be wave-uniform-base + lane*16.
#define GLDS16(g, l)                                                        \
    __builtin_amdgcn_global_load_lds(                                       \
        (const __attribute__((address_space(1))) void*)(g),                 \
        (__attribute__((address_space(3))) void*)(l), 16, 0, 0)

// ---------------------------------------------------------------------------
__global__ void conv_f2b(const float* __restrict__ src, unsigned short* __restrict__ dst, int n4) {
    int i = blockIdx.x * 256 + threadIdx.x;
    if (i < n4) {
        float4 v = ((const float4*)src)[i];
        ushort4 o;
        o.x = f2b(v.x); o.y = f2b(v.y); o.z = f2b(v.z); o.w = f2b(v.w);
        ((ushort4*)dst)[i] = o;
    }
}

__global__ void zero_u4(uint4* __restrict__ p, int n4) {
    int i = blockIdx.x * 256 + threadIdx.x;
    if (i < n4) p[i] = make_uint4(0u, 0u, 0u, 0u);
}

// ---------------------------------------------------------------------------
// MFMA compute on one staged (A[128][64], B[192][64]) LDS pair.
// Gates r,z go to acc[0],acc[1]; third gate (i_n or h_n) to acc[G2].
template<int G2>
__device__ __forceinline__ void mma_tile(
    const unsigned char* __restrict__ lds_a, const unsigned char* __restrict__ lds_b,
    f32x4 acc[4][2][2], int wm, int wn, int l15, int hi8)
{
    #pragma unroll
    for (int kk = 0; kk < 2; ++kk) {
        const int kb = kk * 64 + hi8 * 2;
        bf16x8 a[2];
        #pragma unroll
        for (int mi = 0; mi < 2; ++mi) {
            int row = wm * 32 + mi * 16 + l15;
            a[mi] = *(const bf16x8*)(lds_a + row * 128 + (kb ^ ((row & 7) << 4)));
        }
        #pragma unroll
        for (int g = 0; g < 3; ++g) {
            const int gi = (g == 2) ? G2 : g;
            bf16x8 b[2];
            #pragma unroll
            for (int ni = 0; ni < 2; ++ni) {
                int brow = g * 64 + wn * 32 + ni * 16 + l15;
                b[ni] = *(const bf16x8*)(lds_b + brow * 128 + (kb ^ ((brow & 7) << 4)));
            }
            #pragma unroll
            for (int mi = 0; mi < 2; ++mi)
                #pragma unroll
                for (int ni = 0; ni < 2; ++ni)
                    acc[gi][mi][ni] = __builtin_amdgcn_mfma_f32_16x16x32_bf16(
                        a[mi], b[ni], acc[gi][mi][ni], 0, 0, 0);
        }
    }
}

// ---------------------------------------------------------------------------
// One GRU step as a tiled GEMM. Block: 512 thr (8 waves = 4M x 2N),
// tile = 128 edges x 64 cols x {r, z, i_n, h_n}. K staged in BK=64 chunks via
// global_load_lds (pre-swizzled source -> XOR-swizzled LDS reads).
__global__ __launch_bounds__(512, 4) void gru_step(
    const unsigned short* __restrict__ feat16,   // [NN, 64] bf16
    const int* __restrict__ emi,                 // [E, 3]
    const unsigned short* __restrict__ hprev,    // [E, 512] bf16 (t>0)
    unsigned short* __restrict__ hnext,          // [E, 512] bf16
    const unsigned short* __restrict__ wih,      // [1536, 64] bf16
    const unsigned short* __restrict__ whh,      // [1536, 512] bf16
    const float* __restrict__ bih,
    const float* __restrict__ bhh,
    int t)
{
    __shared__ __align__(16) unsigned char lds_a[128 * 128];   // 128 rows x 64 bf16, swizzled
    __shared__ __align__(16) unsigned char lds_b[192 * 128];   // 192 rows x 64 bf16, swizzled

    const int tid = threadIdx.x;
    // bijective XCD swizzle: 8 n-tiles of an m-tile land on one XCD (nwg%8==0)
    const int nwg = gridDim.x;
    const int logical = (blockIdx.x & 7) * (nwg >> 3) + (blockIdx.x >> 3);
    const int mb = (logical >> 3) * 128;
    const int nb = (logical & 7) * 64;

    const int lane = tid & 63;
    const int wid  = tid >> 6;
    const int wm   = wid >> 1;
    const int wn   = wid & 1;
    const int l15  = lane & 15;
    const int hi8  = (lane >> 4) * 8;

    f32x4 acc[4][2][2];
    #pragma unroll
    for (int g = 0; g < 4; ++g)
        #pragma unroll
        for (int mi = 0; mi < 2; ++mi)
            #pragma unroll
            for (int ni = 0; ni < 2; ++ni) {
                f32x4 zz = {0.f, 0.f, 0.f, 0.f};
                acc[g][mi][ni] = zz;
            }

    // per-thread staging coordinates (hoisted; constant across k-steps)
    // A: 1024 16B chunks (2/thread); B: 1536 chunks (3/thread)
    int a_row[2], a_sl2[2], a_er[2];
    #pragma unroll
    for (int q = 0; q < 2; ++q) {
        int c = tid + q * 512;
        a_row[q] = c >> 3;
        a_sl2[q] = (c & 7) ^ (a_row[q] & 7);
        int er = mb + a_row[q];
        a_er[q] = er < E_N ? er : E_N - 1;
    }
    int b_wr[3], b_sl2[3];
    #pragma unroll
    for (int q = 0; q < 3; ++q) {
        int c = tid + q * 512;
        int row = c >> 3;
        b_sl2[q] = (c & 7) ^ (row & 7);
        b_wr[q]  = (row >> 6) * 512 + nb + (row & 63);
    }

    // ---------------- x-phase: x @ W_ih^T (K = 64) ----------------
    #pragma unroll
    for (int q = 0; q < 2; ++q) {
        int node = emi[a_er[q] * 3 + t];
        GLDS16(feat16 + (size_t)node * 64 + a_sl2[q] * 8, lds_a + (tid + q * 512) * 16);
    }
    #pragma unroll
    for (int q = 0; q < 3; ++q)
        GLDS16(wih + (size_t)b_wr[q] * 64 + b_sl2[q] * 8, lds_b + (tid + q * 512) * 16);
    __syncthreads();
    mma_tile<2>(lds_a, lds_b, acc, wm, wn, l15, hi8);
    __syncthreads();

    // ---------------- h-phase: h @ W_hh^T (K = 512, 8 steps) ----------------
    if (t > 0) {
        const unsigned short* asrc[2];
        const unsigned short* bsrc[3];
        #pragma unroll
        for (int q = 0; q < 2; ++q) asrc[q] = hprev + (size_t)a_er[q] * 512 + a_sl2[q] * 8;
        #pragma unroll
        for (int q = 0; q < 3; ++q) bsrc[q] = whh + (size_t)b_wr[q] * 512 + b_sl2[q] * 8;

        for (int kt = 0; kt < 8; ++kt) {
            const int k0 = kt * 64;
            #pragma unroll
            for (int q = 0; q < 2; ++q)
                GLDS16(asrc[q] + k0, lds_a + (tid + q * 512) * 16);
            #pragma unroll
            for (int q = 0; q < 3; ++q)
                GLDS16(bsrc[q] + k0, lds_b + (tid + q * 512) * 16);
            __syncthreads();
            mma_tile<3>(lds_a, lds_b, acc, wm, wn, l15, hi8);
            __syncthreads();
        }
    }

    // ---------------- epilogue: gate math + bf16 store ----------------
    #pragma unroll
    for (int ni = 0; ni < 2; ++ni) {
        const int col = nb + wn * 32 + ni * 16 + l15;
        const float br0  = bih[col] + bhh[col];
        const float bz0  = bih[512 + col] + bhh[512 + col];
        const float bin_ = bih[1024 + col];
        const float bhn_ = bhh[1024 + col];
        #pragma unroll
        for (int mi = 0; mi < 2; ++mi) {
            const int rbase = mb + wm * 32 + mi * 16 + (lane >> 4) * 4;
            #pragma unroll
            for (int j = 0; j < 4; ++j) {
                const int row = rbase + j;
                if (row < E_N) {
                    float r = fsig(acc[0][mi][ni][j] + br0);
                    float z = fsig(acc[1][mi][ni][j] + bz0);
                    float n = ftanhf(acc[2][mi][ni][j] + bin_ + r * (acc[3][mi][ni][j] + bhn_));
                    float hold = (t > 0) ? b2f(hprev[(size_t)row * 512 + col]) : 0.f;
                    float hv = (1.f - z) * n + z * hold;
                    hnext[(size_t)row * 512 + col] = f2b(hv);
                }
            }
        }
    }
}

// ---------------------------------------------------------------------------
__global__ __launch_bounds__(256) void attn_logits(
    const unsigned short* __restrict__ hl, const float* __restrict__ attnw,
    const int* __restrict__ dstp, float* __restrict__ a, unsigned int* __restrict__ amax)
{
    int e = blockIdx.x * 4 + (threadIdx.x >> 6);
    int lane = threadIdx.x & 63;
    uint4 v = *(const uint4*)(hl + (size_t)e * 512 + lane * 8);
    int h = lane >> 3;
    int dp = (lane & 7) * 8;
    float4 w0 = *(const float4*)(attnw + h * 64 + dp);
    float4 w1 = *(const float4*)(attnw + h * 64 + dp + 4);
    const unsigned short* u = (const unsigned short*)&v;
    float s = b2f(u[0]) * w0.x + b2f(u[1]) * w0.y + b2f(u[2]) * w0.z + b2f(u[3]) * w0.w
            + b2f(u[4]) * w1.x + b2f(u[5]) * w1.y + b2f(u[6]) * w1.z + b2f(u[7]) * w1.w;
    s += __shfl_xor(s, 1);
    s += __shfl_xor(s, 2);
    s += __shfl_xor(s, 4);
    if ((lane & 7) == 0) {
        float av = s > 0.f ? s : 0.01f * s;
        a[e * 8 + h] = av;
        atomicMax(&amax[dstp[e] * 8 + h], mono(av));
    }
}

__global__ __launch_bounds__(256) void attn_exp(
    const int* __restrict__ dstp, float* __restrict__ a,
    const unsigned int* __restrict__ amax, float* __restrict__ asum)
{
    int i = blockIdx.x * 256 + threadIdx.x;   // E*8 exact
    int e = i >> 3, h = i & 7;
    int d = dstp[e];
    float m = unmono(amax[d * 8 + h]);
    float p = __expf(a[i] - m);
    a[i] = p;
    atomicAdd(&asum[d * 8 + h], p);
}

__global__ __launch_bounds__(256) void scatter_out(
    const unsigned short* __restrict__ hl, const int* __restrict__ dstp,
    const float* __restrict__ a, const float* __restrict__ asum,
    float* __restrict__ out)
{
    int i = blockIdx.x * 256 + threadIdx.x;   // E*128 exact
    int e = i >> 7;
    int q = i & 127;
    int c0 = q * 4, h = q >> 4;
    int d = dstp[e];
    float alpha = a[e * 8 + h] * frcp(asum[d * 8 + h]);
    uint2 v = *(const uint2*)(hl + (size_t)e * 512 + c0);
    float* op = out + (size_t)d * 512 + c0;
    atomicAdd(op + 0, b2f((unsigned short)(v.x & 0xffffu)) * alpha);
    atomicAdd(op + 1, b2f((unsigned short)(v.x >> 16)) * alpha);
    atomicAdd(op + 2, b2f((unsigned short)(v.y & 0xffffu)) * alpha);
    atomicAdd(op + 3, b2f((unsigned short)(v.y >> 16)) * alpha);
}

// ---------------------------------------------------------------------------
extern "C" void kernel_launch(void* const* d_in, const int* in_sizes, int n_in,
                              void* d_out, int out_size, void* d_ws, size_t ws_size,
                              hipStream_t stream)
{
    const float* features = (const float*)d_in[0];
    const float* W_ih     = (const float*)d_in[1];
    const float* W_hh     = (const float*)d_in[2];
    const float* b_ih     = (const float*)d_in[3];
    const float* b_hh     = (const float*)d_in[4];
    const float* attnw    = (const float*)d_in[5];
    const int*   emi      = (const int*)d_in[6];
    const int*   dstp     = (const int*)d_in[7];

    char* ws = (char*)d_ws;
    size_t off = 0;
    auto alloc = [&](size_t bytes) -> void* {
        void* p = ws + off;
        off = (off + bytes + 255) & ~(size_t)255;
        return p;
    };
    unsigned short* feat16 = (unsigned short*)alloc((size_t)NN_N * 64 * 2);
    unsigned short* wih16  = (unsigned short*)alloc((size_t)1536 * 64 * 2);
    unsigned short* whh16  = (unsigned short*)alloc((size_t)1536 * 512 * 2);
    unsigned short* h0     = (unsigned short*)alloc((size_t)E_N * 512 * 2);
    unsigned short* h1     = (unsigned short*)alloc((size_t)E_N * 512 * 2);
    float*          abuf   = (float*)alloc((size_t)E_N * 8 * 4);
    unsigned int*   amax   = (unsigned int*)alloc((size_t)ND_N * 8 * 4);
    float*          asum   = (float*)alloc((size_t)ND_N * 8 * 4);

    conv_f2b<<<(NN_N * 64 / 4 + 255) / 256, 256, 0, stream>>>(features, feat16, NN_N * 64 / 4);
    conv_f2b<<<(1536 * 64 / 4 + 255) / 256, 256, 0, stream>>>(W_ih, wih16, 1536 * 64 / 4);
    conv_f2b<<<(1536 * 512 / 4 + 255) / 256, 256, 0, stream>>>(W_hh, whh16, 1536 * 512 / 4);

    zero_u4<<<(out_size / 4 + 255) / 256, 256, 0, stream>>>((uint4*)d_out, out_size / 4);
    zero_u4<<<(ND_N * 8 * 2 / 4 + 255) / 256, 256, 0, stream>>>((uint4*)amax, ND_N * 8 * 2 / 4);

    // GRU: 3 steps; grid = 782 m-tiles x 8 n-tiles = 6256 (divisible by 8)
    const int grid = ((E_N + 127) / 128) * 8;
    gru_step<<<grid, 512, 0, stream>>>(feat16, emi, nullptr, h0, wih16, whh16, b_ih, b_hh, 0);
    gru_step<<<grid, 512, 0, stream>>>(feat16, emi, h0, h1, wih16, whh16, b_ih, b_hh, 1);
    gru_step<<<grid, 512, 0, stream>>>(feat16, emi, h1, h0, wih16, whh16, b_ih, b_hh, 2);

    attn_logits<<<E_N / 4, 256, 0, stream>>>(h0, attnw, dstp, abuf, amax);
    attn_exp<<<E_N * 8 / 256, 256, 0, stream>>>(dstp, abuf, amax, asum);
    scatter_out<<<E_N * 128 / 256, 256, 0, stream>>>(h0, dstp, abuf, asum, (float*)d_out);
}

// Round 7
// 809.265 us; speedup vs baseline: 2.9023x; 1.7921x over previous
//
#include <hip/hip_runtime.h>

typedef __attribute__((ext_vector_type(8))) short bf16x8;
typedef __attribute__((ext_vector_type(4))) float f32x4;

#define E_N   100000
#define ND_N  50000
#define NN_N  100000
#define SLOTS 32

__device__ __forceinline__ float b2f(unsigned short u) {
    return __uint_as_float(((unsigned int)u) << 16);
}
__device__ __forceinline__ unsigned short f2b(float f) {
    unsigned int b = __float_as_uint(f);
    b += 0x7fffu + ((b >> 16) & 1u);
    return (unsigned short)(b >> 16);
}
__device__ __forceinline__ float frcp(float x) { return __builtin_amdgcn_rcpf(x); }
__device__ __forceinline__ float fsig(float x) { return frcp(1.f + __expf(-x)); }
__device__ __forceinline__ float ftanhf(float x) {
    float e = __expf(2.f * x);
    return 1.f - 2.f * frcp(e + 1.f);
}

// async global->LDS, 16B per lane. LDS dest must be wave-uniform-base + lane*16.
#define GLDS16(g, l)                                                        \
    __builtin_amdgcn_global_load_lds(                                       \
        (const __attribute__((address_space(1))) void*)(g),                 \
        (__attribute__((address_space(3))) void*)(l), 16, 0, 0)

// ---------------------------------------------------------------------------
__global__ void conv_f2b(const float* __restrict__ src, unsigned short* __restrict__ dst, int n4) {
    int i = blockIdx.x * 256 + threadIdx.x;
    if (i < n4) {
        float4 v = ((const float4*)src)[i];
        ushort4 o;
        o.x = f2b(v.x); o.y = f2b(v.y); o.z = f2b(v.z); o.w = f2b(v.w);
        ((ushort4*)dst)[i] = o;
    }
}

__global__ void zero_u4(uint4* __restrict__ p, int n4) {
    int i = blockIdx.x * 256 + threadIdx.x;
    if (i < n4) p[i] = make_uint4(0u, 0u, 0u, 0u);
}

// ---------------------------------------------------------------------------
// MFMA compute on one staged (A[128][64], B[192][64]) LDS pair.
// Gates r,z go to acc[0],acc[1]; third gate (i_n or h_n) to acc[G2].
template<int G2>
__device__ __forceinline__ void mma_tile(
    const unsigned char* __restrict__ lds_a, const unsigned char* __restrict__ lds_b,
    f32x4 acc[4][2][2], int wm, int wn, int l15, int hi8)
{
    #pragma unroll
    for (int kk = 0; kk < 2; ++kk) {
        const int kb = kk * 64 + hi8 * 2;
        bf16x8 a[2];
        #pragma unroll
        for (int mi = 0; mi < 2; ++mi) {
            int row = wm * 32 + mi * 16 + l15;
            a[mi] = *(const bf16x8*)(lds_a + row * 128 + (kb ^ ((row & 7) << 4)));
        }
        #pragma unroll
        for (int g = 0; g < 3; ++g) {
            const int gi = (g == 2) ? G2 : g;
            bf16x8 b[2];
            #pragma unroll
            for (int ni = 0; ni < 2; ++ni) {
                int brow = g * 64 + wn * 32 + ni * 16 + l15;
                b[ni] = *(const bf16x8*)(lds_b + brow * 128 + (kb ^ ((brow & 7) << 4)));
            }
            #pragma unroll
            for (int mi = 0; mi < 2; ++mi)
                #pragma unroll
                for (int ni = 0; ni < 2; ++ni)
                    acc[gi][mi][ni] = __builtin_amdgcn_mfma_f32_16x16x32_bf16(
                        a[mi], b[ni], acc[gi][mi][ni], 0, 0, 0);
        }
    }
}

// ---------------------------------------------------------------------------
// One GRU step as a tiled GEMM. Block: 512 thr (8 waves = 4M x 2N),
// tile = 128 edges x 64 cols x {r, z, i_n, h_n}. K staged in BK=64 chunks via
// global_load_lds (pre-swizzled source -> XOR-swizzled LDS reads).
__global__ __launch_bounds__(512, 4) void gru_step(
    const unsigned short* __restrict__ feat16,   // [NN, 64] bf16
    const int* __restrict__ emi,                 // [E, 3]
    const unsigned short* __restrict__ hprev,    // [E, 512] bf16 (t>0)
    unsigned short* __restrict__ hnext,          // [E, 512] bf16
    const unsigned short* __restrict__ wih,      // [1536, 64] bf16
    const unsigned short* __restrict__ whh,      // [1536, 512] bf16
    const float* __restrict__ bih,
    const float* __restrict__ bhh,
    int t)
{
    __shared__ __align__(16) unsigned char lds_a[128 * 128];   // 128 rows x 64 bf16, swizzled
    __shared__ __align__(16) unsigned char lds_b[192 * 128];   // 192 rows x 64 bf16, swizzled

    const int tid = threadIdx.x;
    // bijective XCD swizzle: 8 n-tiles of an m-tile land on one XCD (nwg%8==0)
    const int nwg = gridDim.x;
    const int logical = (blockIdx.x & 7) * (nwg >> 3) + (blockIdx.x >> 3);
    const int mb = (logical >> 3) * 128;
    const int nb = (logical & 7) * 64;

    const int lane = tid & 63;
    const int wid  = tid >> 6;
    const int wm   = wid >> 1;
    const int wn   = wid & 1;
    const int l15  = lane & 15;
    const int hi8  = (lane >> 4) * 8;

    f32x4 acc[4][2][2];
    #pragma unroll
    for (int g = 0; g < 4; ++g)
        #pragma unroll
        for (int mi = 0; mi < 2; ++mi)
            #pragma unroll
            for (int ni = 0; ni < 2; ++ni) {
                f32x4 zz = {0.f, 0.f, 0.f, 0.f};
                acc[g][mi][ni] = zz;
            }

    // per-thread staging coordinates (hoisted; constant across k-steps)
    int a_row[2], a_sl2[2], a_er[2];
    #pragma unroll
    for (int q = 0; q < 2; ++q) {
        int c = tid + q * 512;
        a_row[q] = c >> 3;
        a_sl2[q] = (c & 7) ^ (a_row[q] & 7);
        int er = mb + a_row[q];
        a_er[q] = er < E_N ? er : E_N - 1;
    }
    int b_wr[3], b_sl2[3];
    #pragma unroll
    for (int q = 0; q < 3; ++q) {
        int c = tid + q * 512;
        int row = c >> 3;
        b_sl2[q] = (c & 7) ^ (row & 7);
        b_wr[q]  = (row >> 6) * 512 + nb + (row & 63);
    }

    // ---------------- x-phase: x @ W_ih^T (K = 64) ----------------
    #pragma unroll
    for (int q = 0; q < 2; ++q) {
        int node = emi[a_er[q] * 3 + t];
        GLDS16(feat16 + (size_t)node * 64 + a_sl2[q] * 8, lds_a + (tid + q * 512) * 16);
    }
    #pragma unroll
    for (int q = 0; q < 3; ++q)
        GLDS16(wih + (size_t)b_wr[q] * 64 + b_sl2[q] * 8, lds_b + (tid + q * 512) * 16);
    __syncthreads();
    mma_tile<2>(lds_a, lds_b, acc, wm, wn, l15, hi8);
    __syncthreads();

    // ---------------- h-phase: h @ W_hh^T (K = 512, 8 steps) ----------------
    if (t > 0) {
        const unsigned short* asrc[2];
        const unsigned short* bsrc[3];
        #pragma unroll
        for (int q = 0; q < 2; ++q) asrc[q] = hprev + (size_t)a_er[q] * 512 + a_sl2[q] * 8;
        #pragma unroll
        for (int q = 0; q < 3; ++q) bsrc[q] = whh + (size_t)b_wr[q] * 512 + b_sl2[q] * 8;

        for (int kt = 0; kt < 8; ++kt) {
            const int k0 = kt * 64;
            #pragma unroll
            for (int q = 0; q < 2; ++q)
                GLDS16(asrc[q] + k0, lds_a + (tid + q * 512) * 16);
            #pragma unroll
            for (int q = 0; q < 3; ++q)
                GLDS16(bsrc[q] + k0, lds_b + (tid + q * 512) * 16);
            __syncthreads();
            mma_tile<3>(lds_a, lds_b, acc, wm, wn, l15, hi8);
            __syncthreads();
        }
    }

    // ---------------- epilogue: gate math + bf16 store ----------------
    #pragma unroll
    for (int ni = 0; ni < 2; ++ni) {
        const int col = nb + wn * 32 + ni * 16 + l15;
        const float br0  = bih[col] + bhh[col];
        const float bz0  = bih[512 + col] + bhh[512 + col];
        const float bin_ = bih[1024 + col];
        const float bhn_ = bhh[1024 + col];
        #pragma unroll
        for (int mi = 0; mi < 2; ++mi) {
            const int rbase = mb + wm * 32 + mi * 16 + (lane >> 4) * 4;
            #pragma unroll
            for (int j = 0; j < 4; ++j) {
                const int row = rbase + j;
                if (row < E_N) {
                    float r = fsig(acc[0][mi][ni][j] + br0);
                    float z = fsig(acc[1][mi][ni][j] + bz0);
                    float n = ftanhf(acc[2][mi][ni][j] + bin_ + r * (acc[3][mi][ni][j] + bhn_));
                    float hold = (t > 0) ? b2f(hprev[(size_t)row * 512 + col]) : 0.f;
                    float hv = (1.f - z) * n + z * hold;
                    hnext[(size_t)row * 512 + col] = f2b(hv);
                }
            }
        }
    }
}

// ---------------------------------------------------------------------------
// attention logits + leaky relu (no atomics). One wave per edge;
// 8-lane groups own one head each.
__global__ __launch_bounds__(256) void attn_logits(
    const unsigned short* __restrict__ hl, const float* __restrict__ attnw,
    float* __restrict__ a)
{
    int e = blockIdx.x * 4 + (threadIdx.x >> 6);
    int lane = threadIdx.x & 63;
    uint4 v = *(const uint4*)(hl + (size_t)e * 512 + lane * 8);
    int h = lane >> 3;
    int dp = (lane & 7) * 8;
    float4 w0 = *(const float4*)(attnw + h * 64 + dp);
    float4 w1 = *(const float4*)(attnw + h * 64 + dp + 4);
    const unsigned short* u = (const unsigned short*)&v;
    float s = b2f(u[0]) * w0.x + b2f(u[1]) * w0.y + b2f(u[2]) * w0.z + b2f(u[3]) * w0.w
            + b2f(u[4]) * w1.x + b2f(u[5]) * w1.y + b2f(u[6]) * w1.z + b2f(u[7]) * w1.w;
    s += __shfl_xor(s, 1);
    s += __shfl_xor(s, 2);
    s += __shfl_xor(s, 4);
    if ((lane & 7) == 0)
        a[e * 8 + h] = s > 0.f ? s : 0.01f * s;
}

// per-dst edge lists (order within a list is arbitrary)
__global__ __launch_bounds__(256) void build_lists(
    const int* __restrict__ dstp, int* __restrict__ cnt, int* __restrict__ lists)
{
    int e = blockIdx.x * 256 + threadIdx.x;
    if (e < E_N) {
        int d = dstp[e];
        int slot = atomicAdd(&cnt[d], 1);
        if (slot < SLOTS) lists[(size_t)d * SLOTS + slot] = e;
    }
}

// One wave per dst: segment softmax over its edges + weighted gather-sum.
// Lane owns 8 contiguous cols (all within head h = lane>>3) -> softmax state
// is lane-local; output written with plain coalesced stores (no atomics).
__global__ __launch_bounds__(256) void aggregate(
    const unsigned short* __restrict__ hl, const float* __restrict__ a,
    const int* __restrict__ lists, const int* __restrict__ cnt,
    float* __restrict__ out)
{
    int d = blockIdx.x * 4 + (threadIdx.x >> 6);
    int lane = threadIdx.x & 63;
    int n = cnt[d];
    n = n < SLOTS ? n : SLOTS;
    const int h = lane >> 3;
    const int* lst = lists + (size_t)d * SLOTS;

    float m = -1e30f;
    for (int i = 0; i < n; ++i)
        m = fmaxf(m, a[lst[i] * 8 + h]);
    float s = 0.f;
    for (int i = 0; i < n; ++i)
        s += __expf(a[lst[i] * 8 + h] - m);
    float rs = frcp(s);

    float acc[8] = {0.f, 0.f, 0.f, 0.f, 0.f, 0.f, 0.f, 0.f};
    for (int i = 0; i < n; ++i) {
        int e = lst[i];
        float alpha = __expf(a[e * 8 + h] - m) * rs;
        uint4 v = *(const uint4*)(hl + (size_t)e * 512 + lane * 8);
        const unsigned short* u = (const unsigned short*)&v;
        #pragma unroll
        for (int j = 0; j < 8; ++j)
            acc[j] += alpha * b2f(u[j]);
    }
    float4 o0 = {acc[0], acc[1], acc[2], acc[3]};
    float4 o1 = {acc[4], acc[5], acc[6], acc[7]};
    float* op = out + (size_t)d * 512 + lane * 8;
    *(float4*)op = o0;
    *(float4*)(op + 4) = o1;
}

// ---------------------------------------------------------------------------
extern "C" void kernel_launch(void* const* d_in, const int* in_sizes, int n_in,
                              void* d_out, int out_size, void* d_ws, size_t ws_size,
                              hipStream_t stream)
{
    const float* features = (const float*)d_in[0];
    const float* W_ih     = (const float*)d_in[1];
    const float* W_hh     = (const float*)d_in[2];
    const float* b_ih     = (const float*)d_in[3];
    const float* b_hh     = (const float*)d_in[4];
    const float* attnw    = (const float*)d_in[5];
    const int*   emi      = (const int*)d_in[6];
    const int*   dstp     = (const int*)d_in[7];

    char* ws = (char*)d_ws;
    size_t off = 0;
    auto alloc = [&](size_t bytes) -> void* {
        void* p = ws + off;
        off = (off + bytes + 255) & ~(size_t)255;
        return p;
    };
    unsigned short* feat16 = (unsigned short*)alloc((size_t)NN_N * 64 * 2);
    unsigned short* wih16  = (unsigned short*)alloc((size_t)1536 * 64 * 2);
    unsigned short* whh16  = (unsigned short*)alloc((size_t)1536 * 512 * 2);
    unsigned short* h0     = (unsigned short*)alloc((size_t)E_N * 512 * 2);
    unsigned short* h1     = (unsigned short*)alloc((size_t)E_N * 512 * 2);
    float*          abuf   = (float*)alloc((size_t)E_N * 8 * 4);
    int*            cnt    = (int*)alloc((size_t)ND_N * 4);
    int*            lists  = (int*)alloc((size_t)ND_N * SLOTS * 4);

    conv_f2b<<<(NN_N * 64 / 4 + 255) / 256, 256, 0, stream>>>(features, feat16, NN_N * 64 / 4);
    conv_f2b<<<(1536 * 64 / 4 + 255) / 256, 256, 0, stream>>>(W_ih, wih16, 1536 * 64 / 4);
    conv_f2b<<<(1536 * 512 / 4 + 255) / 256, 256, 0, stream>>>(W_hh, whh16, 1536 * 512 / 4);

    zero_u4<<<(ND_N / 4 + 255) / 256, 256, 0, stream>>>((uint4*)cnt, ND_N / 4);

    // GRU: 3 steps; grid = 782 m-tiles x 8 n-tiles = 6256 (divisible by 8)
    const int grid = ((E_N + 127) / 128) * 8;
    gru_step<<<grid, 512, 0, stream>>>(feat16, emi, nullptr, h0, wih16, whh16, b_ih, b_hh, 0);
    gru_step<<<grid, 512, 0, stream>>>(feat16, emi, h0, h1, wih16, whh16, b_ih, b_hh, 1);
    gru_step<<<grid, 512, 0, stream>>>(feat16, emi, h1, h0, wih16, whh16, b_ih, b_hh, 2);

    // attention + dst-gather softmax/aggregation (no output atomics)
    attn_logits<<<E_N / 4, 256, 0, stream>>>(h0, attnw, abuf);
    build_lists<<<(E_N + 255) / 256, 256, 0, stream>>>(dstp, cnt, lists);
    aggregate<<<ND_N / 4, 256, 0, stream>>>(h0, abuf, lists, cnt, (float*)d_out);
}

// Round 9
// 740.781 us; speedup vs baseline: 3.1706x; 1.0924x over previous
//
#include <hip/hip_runtime.h>

typedef __attribute__((ext_vector_type(8))) short bf16x8;
typedef __attribute__((ext_vector_type(4))) float f32x4;

#define E_N   100000
#define ND_N  50000
#define NN_N  100000
#define SLOTS 32

__device__ __forceinline__ float b2f(unsigned short u) {
    return __uint_as_float(((unsigned int)u) << 16);
}
__device__ __forceinline__ unsigned short f2b(float f) {
    unsigned int b = __float_as_uint(f);
    b += 0x7fffu + ((b >> 16) & 1u);
    return (unsigned short)(b >> 16);
}
__device__ __forceinline__ float frcp(float x) { return __builtin_amdgcn_rcpf(x); }
__device__ __forceinline__ float fsig(float x) { return frcp(1.f + __expf(-x)); }
__device__ __forceinline__ float ftanhf(float x) {
    float e = __expf(2.f * x);
    return 1.f - 2.f * frcp(e + 1.f);
}

// async global->LDS, 16B per lane. LDS dest must be wave-uniform-base + lane*16.
#define GLDS16(g, l)                                                        \
    __builtin_amdgcn_global_load_lds(                                       \
        (const __attribute__((address_space(1))) void*)(g),                 \
        (__attribute__((address_space(3))) void*)(l), 16, 0, 0)

__device__ __forceinline__ void wait_and_barrier() {
    __builtin_amdgcn_sched_barrier(0);
    asm volatile("s_waitcnt vmcnt(0)" ::: "memory");
    __builtin_amdgcn_s_barrier();
    __builtin_amdgcn_sched_barrier(0);
}
__device__ __forceinline__ void plain_barrier() {
    __builtin_amdgcn_sched_barrier(0);
    __builtin_amdgcn_s_barrier();
    __builtin_amdgcn_sched_barrier(0);
}

// ---------------------------------------------------------------------------
__global__ void conv_f2b(const float* __restrict__ src, unsigned short* __restrict__ dst, int n4) {
    int i = blockIdx.x * 256 + threadIdx.x;
    if (i < n4) {
        float4 v = ((const float4*)src)[i];
        ushort4 o;
        o.x = f2b(v.x); o.y = f2b(v.y); o.z = f2b(v.z); o.w = f2b(v.w);
        ((ushort4*)dst)[i] = o;
    }
}

__global__ void zero_u4(uint4* __restrict__ p, int n4) {
    int i = blockIdx.x * 256 + threadIdx.x;
    if (i < n4) p[i] = make_uint4(0u, 0u, 0u, 0u);
}

// ---------------------------------------------------------------------------
// MFMA on one staged buffer: A[128 rows][64k] at +0, B[192 rows][64k] at +16384.
// Gates r,z -> acc[0],acc[1]; third gate group -> acc[G2] (2=i_n for x, 3=h_n for h).
template<int G2>
__device__ __forceinline__ void mma_tile(
    const unsigned char* __restrict__ buf,
    f32x4 acc[4][2][2], int wm, int wn, int l15, int hi8)
{
    const unsigned char* lds_a = buf;
    const unsigned char* lds_b = buf + 16384;
    #pragma unroll
    for (int kk = 0; kk < 2; ++kk) {
        const int kb = kk * 64 + hi8 * 2;
        bf16x8 a[2];
        #pragma unroll
        for (int mi = 0; mi < 2; ++mi) {
            int row = wm * 32 + mi * 16 + l15;
            a[mi] = *(const bf16x8*)(lds_a + row * 128 + (kb ^ ((row & 7) << 4)));
        }
        #pragma unroll
        for (int g = 0; g < 3; ++g) {
            const int gi = (g == 2) ? G2 : g;
            bf16x8 b[2];
            #pragma unroll
            for (int ni = 0; ni < 2; ++ni) {
                int brow = g * 64 + wn * 32 + ni * 16 + l15;
                b[ni] = *(const bf16x8*)(lds_b + brow * 128 + (kb ^ ((brow & 7) << 4)));
            }
            #pragma unroll
            for (int mi = 0; mi < 2; ++mi)
                #pragma unroll
                for (int ni = 0; ni < 2; ++ni)
                    acc[gi][mi][ni] = __builtin_amdgcn_mfma_f32_16x16x32_bf16(
                        a[mi], b[ni], acc[gi][mi][ni], 0, 0, 0);
        }
    }
}

// ---------------------------------------------------------------------------
// GRU step, tiled GEMM, double-buffered LDS (T3-minimal 2-phase pipeline).
// Block: 512 thr (8 waves = 4M x 2N), tile = 128 edges x 64 cols x {r,z,n}.
__global__ __launch_bounds__(512, 4) void gru_step(
    const unsigned short* __restrict__ feat16,   // [NN, 64] bf16
    const int* __restrict__ emi,                 // [E, 3]
    const unsigned short* __restrict__ hprev,    // [E, 512] bf16 (t>0)
    unsigned short* __restrict__ hnext,          // [E, 512] bf16
    const unsigned short* __restrict__ wih,      // [1536, 64] bf16
    const unsigned short* __restrict__ whh,      // [1536, 512] bf16
    const float* __restrict__ bih,
    const float* __restrict__ bhh,
    int t)
{
    // [buf][ A:128x128B=16KB | B:192x128B=24KB ] x 2 = 80KB
    __shared__ __align__(16) unsigned char lds_mem[2 * 40960];

    const int tid = threadIdx.x;
    const int nwg = gridDim.x;
    const int logical = (blockIdx.x & 7) * (nwg >> 3) + (blockIdx.x >> 3);
    const int mb = (logical >> 3) * 128;
    const int nb = (logical & 7) * 64;
    const int hold_kt = nb >> 6;

    const int lane = tid & 63;
    const int wid  = tid >> 6;
    const int wm   = wid >> 1;
    const int wn   = wid & 1;
    const int l15  = lane & 15;
    const int hi8  = (lane >> 4) * 8;

    f32x4 acc[4][2][2];
    #pragma unroll
    for (int g = 0; g < 4; ++g)
        #pragma unroll
        for (int mi = 0; mi < 2; ++mi)
            #pragma unroll
            for (int ni = 0; ni < 2; ++ni) {
                f32x4 zz = {0.f, 0.f, 0.f, 0.f};
                acc[g][mi][ni] = zz;
            }

    // staging coordinates (constant across k-steps)
    int a_sl2[2], a_er[2];
    #pragma unroll
    for (int q = 0; q < 2; ++q) {
        int c = tid + q * 512;
        int row = c >> 3;
        a_sl2[q] = (c & 7) ^ (row & 7);
        int er = mb + row;
        a_er[q] = er < E_N ? er : E_N - 1;
    }
    int b_wr[3], b_sl2[3];
    #pragma unroll
    for (int q = 0; q < 3; ++q) {
        int c = tid + q * 512;
        int row = c >> 3;
        b_sl2[q] = (c & 7) ^ (row & 7);
        b_wr[q]  = (row >> 6) * 512 + nb + (row & 63);
    }

    // ---- prologue: stage x into buf0, h k-tile 0 into buf1 ----
    #pragma unroll
    for (int q = 0; q < 2; ++q) {
        int node = emi[a_er[q] * 3 + t];
        GLDS16(feat16 + (size_t)node * 64 + a_sl2[q] * 8, lds_mem + (tid + q * 512) * 16);
    }
    #pragma unroll
    for (int q = 0; q < 3; ++q)
        GLDS16(wih + (size_t)b_wr[q] * 64 + b_sl2[q] * 8,
               lds_mem + 16384 + (tid + q * 512) * 16);
    if (t > 0) {
        #pragma unroll
        for (int q = 0; q < 2; ++q)
            GLDS16(hprev + (size_t)a_er[q] * 512 + a_sl2[q] * 8,
                   lds_mem + 40960 + (tid + q * 512) * 16);
        #pragma unroll
        for (int q = 0; q < 3; ++q)
            GLDS16(whh + (size_t)b_wr[q] * 512 + b_sl2[q] * 8,
                   lds_mem + 40960 + 16384 + (tid + q * 512) * 16);
    }
    wait_and_barrier();

    // ---- x-phase: x @ W_ih^T (K = 64) from buf0 ----
    mma_tile<2>(lds_mem, acc, wm, wn, l15, hi8);
    plain_barrier();          // buf0 free for k-tile 1's stage

    // packed bf16 h_prev values for the output tile (captured from LDS)
    unsigned int holdp[2][2][2] = {{{0u,0u},{0u,0u}},{{0u,0u},{0u,0u}}};

    // ---- h-phase: h @ W_hh^T, K = 512 in 8 tiles, ping-pong buffers ----
    // k-tile kt read from buf[(kt&1)^1]; k-tile kt+1 staged into buf[kt&1].
    if (t > 0) {
        #pragma unroll
        for (int kt = 0; kt < 8; ++kt) {
            unsigned char*       wr = lds_mem + (kt & 1) * 40960;
            const unsigned char* rd = lds_mem + ((kt & 1) ^ 1) * 40960;
            if (kt < 7) {
                const int k1 = (kt + 1) * 64;
                #pragma unroll
                for (int q = 0; q < 2; ++q)
                    GLDS16(hprev + (size_t)a_er[q] * 512 + k1 + a_sl2[q] * 8,
                           wr + (tid + q * 512) * 16);
                #pragma unroll
                for (int q = 0; q < 3; ++q)
                    GLDS16(whh + (size_t)b_wr[q] * 512 + k1 + b_sl2[q] * 8,
                           wr + 16384 + (tid + q * 512) * 16);
            }
            if (kt == hold_kt) {
                // h_prev tile cols [nb, nb+64) live in rd's A-region right now
                #pragma unroll
                for (int ni = 0; ni < 2; ++ni)
                    #pragma unroll
                    for (int mi = 0; mi < 2; ++mi)
                        #pragma unroll
                        for (int jp = 0; jp < 2; ++jp) {
                            int r0 = wm * 32 + mi * 16 + (lane >> 4) * 4 + jp * 2;
                            int r1 = r0 + 1;
                            int ac = (wn * 32 + ni * 16 + l15) * 2;
                            unsigned int lo = *(const unsigned short*)(rd + r0 * 128 + (ac ^ ((r0 & 7) << 4)));
                            unsigned int hi = *(const unsigned short*)(rd + r1 * 128 + (ac ^ ((r1 & 7) << 4)));
                            holdp[ni][mi][jp] = lo | (hi << 16);
                        }
            }
            mma_tile<3>(rd, acc, wm, wn, l15, hi8);
            wait_and_barrier();   // next buffer staged + all waves done with rd
        }
    }

    // ---- epilogue: gate math -> LDS out tile (reuse buf0.A) -> coalesced store ----
    unsigned char* lout = lds_mem;
    #pragma unroll
    for (int ni = 0; ni < 2; ++ni) {
        const int col = nb + wn * 32 + ni * 16 + l15;
        const float br0  = bih[col] + bhh[col];
        const float bz0  = bih[512 + col] + bhh[512 + col];
        const float bin_ = bih[1024 + col];
        const float bhn_ = bhh[1024 + col];
        #pragma unroll
        for (int mi = 0; mi < 2; ++mi) {
            #pragma unroll
            for (int j = 0; j < 4; ++j) {
                float r = fsig(acc[0][mi][ni][j] + br0);
                float z = fsig(acc[1][mi][ni][j] + bz0);
                float n = ftanhf(acc[2][mi][ni][j] + bin_ + r * (acc[3][mi][ni][j] + bhn_));
                float hold = (t > 0)
                    ? b2f((unsigned short)((holdp[ni][mi][j >> 1] >> ((j & 1) * 16)) & 0xffffu))
                    : 0.f;
                float hv = (1.f - z) * n + z * hold;
                int row = wm * 32 + mi * 16 + (lane >> 4) * 4 + j;
                int oc  = (wn * 32 + ni * 16 + l15) * 2;
                *(unsigned short*)(lout + row * 128 + (oc ^ ((row & 7) << 4))) = f2b(hv);
            }
        }
    }
    __syncthreads();
    #pragma unroll
    for (int q = 0; q < 2; ++q) {
        int chunk = tid + q * 512;
        int row = chunk >> 3, c8 = chunk & 7;
        int grow = mb + row;
        if (grow < E_N) {
            uint4 v = *(const uint4*)(lout + row * 128 + ((c8 * 16) ^ ((row & 7) << 4)));
            *(uint4*)(hnext + (size_t)grow * 512 + nb + c8 * 8) = v;
        }
    }
}

// ---------------------------------------------------------------------------
// attention logits + leaky relu. One wave per edge; 8-lane groups own a head.
__global__ __launch_bounds__(256) void attn_logits(
    const unsigned short* __restrict__ hl, const float* __restrict__ attnw,
    float* __restrict__ a)
{
    int e = blockIdx.x * 4 + (threadIdx.x >> 6);
    int lane = threadIdx.x & 63;
    uint4 v = *(const uint4*)(hl + (size_t)e * 512 + lane * 8);
    int h = lane >> 3;
    int dp = (lane & 7) * 8;
    float4 w0 = *(const float4*)(attnw + h * 64 + dp);
    float4 w1 = *(const float4*)(attnw + h * 64 + dp + 4);
    const unsigned short* u = (const unsigned short*)&v;
    float s = b2f(u[0]) * w0.x + b2f(u[1]) * w0.y + b2f(u[2]) * w0.z + b2f(u[3]) * w0.w
            + b2f(u[4]) * w1.x + b2f(u[5]) * w1.y + b2f(u[6]) * w1.z + b2f(u[7]) * w1.w;
    s += __shfl_xor(s, 1);
    s += __shfl_xor(s, 2);
    s += __shfl_xor(s, 4);
    if ((lane & 7) == 0)
        a[e * 8 + h] = s > 0.f ? s : 0.01f * s;
}

// per-dst edge lists (order within a list is arbitrary)
__global__ __launch_bounds__(256) void build_lists(
    const int* __restrict__ dstp, int* __restrict__ cnt, int* __restrict__ lists)
{
    int e = blockIdx.x * 256 + threadIdx.x;
    if (e < E_N) {
        int d = dstp[e];
        int slot = atomicAdd(&cnt[d], 1);
        if (slot < SLOTS) lists[(size_t)d * SLOTS + slot] = e;
    }
}

// One wave per dst: segment softmax + weighted gather-sum, plain stores.
__global__ __launch_bounds__(256) void aggregate(
    const unsigned short* __restrict__ hl, const float* __restrict__ a,
    const int* __restrict__ lists, const int* __restrict__ cnt,
    float* __restrict__ out)
{
    int d = blockIdx.x * 4 + (threadIdx.x >> 6);
    int lane = threadIdx.x & 63;
    int n = cnt[d];
    n = n < SLOTS ? n : SLOTS;
    const int h = lane >> 3;
    const int* lst = lists + (size_t)d * SLOTS;

    float m = -1e30f;
    for (int i = 0; i < n; ++i)
        m = fmaxf(m, a[lst[i] * 8 + h]);
    float s = 0.f;
    for (int i = 0; i < n; ++i)
        s += __expf(a[lst[i] * 8 + h] - m);
    float rs = frcp(s);

    float acc[8] = {0.f, 0.f, 0.f, 0.f, 0.f, 0.f, 0.f, 0.f};
    for (int i = 0; i < n; ++i) {
        int e = lst[i];
        float alpha = __expf(a[e * 8 + h] - m) * rs;
        uint4 v = *(const uint4*)(hl + (size_t)e * 512 + lane * 8);
        const unsigned short* u = (const unsigned short*)&v;
        #pragma unroll
        for (int j = 0; j < 8; ++j)
            acc[j] += alpha * b2f(u[j]);
    }
    float4 o0 = {acc[0], acc[1], acc[2], acc[3]};
    float4 o1 = {acc[4], acc[5], acc[6], acc[7]};
    float* op = out + (size_t)d * 512 + lane * 8;
    *(float4*)op = o0;
    *(float4*)(op + 4) = o1;
}

// ---------------------------------------------------------------------------
extern "C" void kernel_launch(void* const* d_in, const int* in_sizes, int n_in,
                              void* d_out, int out_size, void* d_ws, size_t ws_size,
                              hipStream_t stream)
{
    const float* features = (const float*)d_in[0];
    const float* W_ih     = (const float*)d_in[1];
    const float* W_hh     = (const float*)d_in[2];
    const float* b_ih     = (const float*)d_in[3];
    const float* b_hh     = (const float*)d_in[4];
    const float* attnw    = (const float*)d_in[5];
    const int*   emi      = (const int*)d_in[6];
    const int*   dstp     = (const int*)d_in[7];

    char* ws = (char*)d_ws;
    size_t off = 0;
    auto alloc = [&](size_t bytes) -> void* {
        void* p = ws + off;
        off = (off + bytes + 255) & ~(size_t)255;
        return p;
    };
    unsigned short* feat16 = (unsigned short*)alloc((size_t)NN_N * 64 * 2);
    unsigned short* wih16  = (unsigned short*)alloc((size_t)1536 * 64 * 2);
    unsigned short* whh16  = (unsigned short*)alloc((size_t)1536 * 512 * 2);
    unsigned short* h0     = (unsigned short*)alloc((size_t)E_N * 512 * 2);
    unsigned short* h1     = (unsigned short*)alloc((size_t)E_N * 512 * 2);
    float*          abuf   = (float*)alloc((size_t)E_N * 8 * 4);
    int*            cnt    = (int*)alloc((size_t)ND_N * 4);
    int*            lists  = (int*)alloc((size_t)ND_N * SLOTS * 4);

    conv_f2b<<<(NN_N * 64 / 4 + 255) / 256, 256, 0, stream>>>(features, feat16, NN_N * 64 / 4);
    conv_f2b<<<(1536 * 64 / 4 + 255) / 256, 256, 0, stream>>>(W_ih, wih16, 1536 * 64 / 4);
    conv_f2b<<<(1536 * 512 / 4 + 255) / 256, 256, 0, stream>>>(W_hh, whh16, 1536 * 512 / 4);

    zero_u4<<<(ND_N / 4 + 255) / 256, 256, 0, stream>>>((uint4*)cnt, ND_N / 4);

    // GRU: 3 steps; grid = 782 m-tiles x 8 n-tiles = 6256 (divisible by 8)
    const int grid = ((E_N + 127) / 128) * 8;
    gru_step<<<grid, 512, 0, stream>>>(feat16, emi, nullptr, h0, wih16, whh16, b_ih, b_hh, 0);
    gru_step<<<grid, 512, 0, stream>>>(feat16, emi, h0, h1, wih16, whh16, b_ih, b_hh, 1);
    gru_step<<<grid, 512, 0, stream>>>(feat16, emi, h1, h0, wih16, whh16, b_ih, b_hh, 2);

    // attention + dst-gather softmax/aggregation (no output atomics)
    attn_logits<<<E_N / 4, 256, 0, stream>>>(h0, attnw, abuf);
    build_lists<<<(E_N + 255) / 256, 256, 0, stream>>>(dstp, cnt, lists);
    aggregate<<<ND_N / 4, 256, 0, stream>>>(h0, abuf, lists, cnt, (float*)d_out);
}

// Round 10
// 739.344 us; speedup vs baseline: 3.1768x; 1.0019x over previous
//
#include <hip/hip_runtime.h>

typedef __attribute__((ext_vector_type(8))) short bf16x8;
typedef __attribute__((ext_vector_type(4))) float f32x4;

#define E_N   100000
#define ND_N  50000
#define NN_N  100000
#define SLOTS 32

__device__ __forceinline__ float b2f(unsigned short u) {
    return __uint_as_float(((unsigned int)u) << 16);
}
__device__ __forceinline__ unsigned short f2b(float f) {
    unsigned int b = __float_as_uint(f);
    b += 0x7fffu + ((b >> 16) & 1u);
    return (unsigned short)(b >> 16);
}
__device__ __forceinline__ float frcp(float x) { return __builtin_amdgcn_rcpf(x); }
__device__ __forceinline__ float fsig(float x) { return frcp(1.f + __expf(-x)); }
__device__ __forceinline__ float ftanhf(float x) {
    float e = __expf(2.f * x);
    return 1.f - 2.f * frcp(e + 1.f);
}

// async global->LDS, 16B per lane. LDS dest must be wave-uniform-base + lane*16.
#define GLDS16(g, l)                                                        \
    __builtin_amdgcn_global_load_lds(                                       \
        (const __attribute__((address_space(1))) void*)(g),                 \
        (__attribute__((address_space(3))) void*)(l), 16, 0, 0)

__device__ __forceinline__ void wait_and_barrier() {
    __builtin_amdgcn_sched_barrier(0);
    asm volatile("s_waitcnt vmcnt(0)" ::: "memory");
    __builtin_amdgcn_s_barrier();
    __builtin_amdgcn_sched_barrier(0);
}
__device__ __forceinline__ void plain_barrier() {
    __builtin_amdgcn_sched_barrier(0);
    __builtin_amdgcn_s_barrier();
    __builtin_amdgcn_sched_barrier(0);
}

// ---------------------------------------------------------------------------
__global__ void conv_f2b(const float* __restrict__ src, unsigned short* __restrict__ dst, int n4) {
    int i = blockIdx.x * 256 + threadIdx.x;
    if (i < n4) {
        float4 v = ((const float4*)src)[i];
        ushort4 o;
        o.x = f2b(v.x); o.y = f2b(v.y); o.z = f2b(v.z); o.w = f2b(v.w);
        ((ushort4*)dst)[i] = o;
    }
}

__global__ void zero_u4(uint4* __restrict__ p, int n4) {
    int i = blockIdx.x * 256 + threadIdx.x;
    if (i < n4) p[i] = make_uint4(0u, 0u, 0u, 0u);
}

// ---------------------------------------------------------------------------
// MFMA on one staged buffer: A[128 rows][64k] at +0, B[192 rows][64k] at +16384.
// Gates r,z -> acc[0],acc[1]; third gate group -> acc[G2] (2=i_n for x, 3=h_n for h).
template<int G2>
__device__ __forceinline__ void mma_tile(
    const unsigned char* __restrict__ buf,
    f32x4 acc[4][2][2], int wm, int wn, int l15, int hi8)
{
    const unsigned char* lds_a = buf;
    const unsigned char* lds_b = buf + 16384;
    #pragma unroll
    for (int kk = 0; kk < 2; ++kk) {
        const int kb = kk * 64 + hi8 * 2;
        bf16x8 a[2];
        #pragma unroll
        for (int mi = 0; mi < 2; ++mi) {
            int row = wm * 32 + mi * 16 + l15;
            a[mi] = *(const bf16x8*)(lds_a + row * 128 + (kb ^ ((row & 7) << 4)));
        }
        #pragma unroll
        for (int g = 0; g < 3; ++g) {
            const int gi = (g == 2) ? G2 : g;
            bf16x8 b[2];
            #pragma unroll
            for (int ni = 0; ni < 2; ++ni) {
                int brow = g * 64 + wn * 32 + ni * 16 + l15;
                b[ni] = *(const bf16x8*)(lds_b + brow * 128 + (kb ^ ((brow & 7) << 4)));
            }
            #pragma unroll
            for (int mi = 0; mi < 2; ++mi)
                #pragma unroll
                for (int ni = 0; ni < 2; ++ni)
                    acc[gi][mi][ni] = __builtin_amdgcn_mfma_f32_16x16x32_bf16(
                        a[mi], b[ni], acc[gi][mi][ni], 0, 0, 0);
        }
    }
}

// ---------------------------------------------------------------------------
// GRU step, tiled GEMM, double-buffered LDS.
// h is stored BLOCKED: h[plane p][E][64] where p = col/64 -> every block's
// h-tile read/write is a contiguous 16KB run (no partial-line HBM traffic).
// Block: 512 thr (8 waves = 4M x 2N), tile = 128 edges x 64 cols x {r,z,n}.
__global__ __launch_bounds__(512, 4) void gru_step(
    const unsigned short* __restrict__ feat16,   // [NN, 64] bf16
    const int* __restrict__ emi,                 // [E, 3]
    const unsigned short* __restrict__ hprev,    // blocked [8][E][64] bf16 (t>0)
    unsigned short* __restrict__ hnext,          // blocked [8][E][64] bf16
    const unsigned short* __restrict__ wih,      // [1536, 64] bf16
    const unsigned short* __restrict__ whh,      // [1536, 512] bf16
    const float* __restrict__ bih,
    const float* __restrict__ bhh,
    int t)
{
    // [buf][ A:128x128B=16KB | B:192x128B=24KB ] x 2 = 80KB
    __shared__ __align__(16) unsigned char lds_mem[2 * 40960];

    const int tid = threadIdx.x;
    const int nwg = gridDim.x;
    const int logical = (blockIdx.x & 7) * (nwg >> 3) + (blockIdx.x >> 3);
    const int mb = (logical >> 3) * 128;
    const int nb = (logical & 7) * 64;
    const int hold_kt = nb >> 6;

    const int lane = tid & 63;
    const int wid  = tid >> 6;
    const int wm   = wid >> 1;
    const int wn   = wid & 1;
    const int l15  = lane & 15;
    const int hi8  = (lane >> 4) * 8;

    f32x4 acc[4][2][2];
    #pragma unroll
    for (int g = 0; g < 4; ++g)
        #pragma unroll
        for (int mi = 0; mi < 2; ++mi)
            #pragma unroll
            for (int ni = 0; ni < 2; ++ni) {
                f32x4 zz = {0.f, 0.f, 0.f, 0.f};
                acc[g][mi][ni] = zz;
            }

    // staging coordinates (constant across k-steps)
    int a_sl2[2], a_er[2];
    #pragma unroll
    for (int q = 0; q < 2; ++q) {
        int c = tid + q * 512;
        int row = c >> 3;
        a_sl2[q] = (c & 7) ^ (row & 7);
        int er = mb + row;
        a_er[q] = er < E_N ? er : E_N - 1;
    }
    int b_wr[3], b_sl2[3];
    #pragma unroll
    for (int q = 0; q < 3; ++q) {
        int c = tid + q * 512;
        int row = c >> 3;
        b_sl2[q] = (c & 7) ^ (row & 7);
        b_wr[q]  = (row >> 6) * 512 + nb + (row & 63);
    }

    // ---- prologue: stage x into buf0, h k-tile 0 into buf1 ----
    #pragma unroll
    for (int q = 0; q < 2; ++q) {
        int node = emi[a_er[q] * 3 + t];
        GLDS16(feat16 + (size_t)node * 64 + a_sl2[q] * 8, lds_mem + (tid + q * 512) * 16);
    }
    #pragma unroll
    for (int q = 0; q < 3; ++q)
        GLDS16(wih + (size_t)b_wr[q] * 64 + b_sl2[q] * 8,
               lds_mem + 16384 + (tid + q * 512) * 16);
    if (t > 0) {
        #pragma unroll
        for (int q = 0; q < 2; ++q)
            GLDS16(hprev + (size_t)a_er[q] * 64 + a_sl2[q] * 8,      // plane 0
                   lds_mem + 40960 + (tid + q * 512) * 16);
        #pragma unroll
        for (int q = 0; q < 3; ++q)
            GLDS16(whh + (size_t)b_wr[q] * 512 + b_sl2[q] * 8,
                   lds_mem + 40960 + 16384 + (tid + q * 512) * 16);
    }
    wait_and_barrier();

    // ---- x-phase: x @ W_ih^T (K = 64) from buf0 ----
    mma_tile<2>(lds_mem, acc, wm, wn, l15, hi8);
    plain_barrier();          // buf0 free for k-tile 1's stage

    // packed bf16 h_prev values for the output tile (captured from LDS)
    unsigned int holdp[2][2][2] = {{{0u,0u},{0u,0u}},{{0u,0u},{0u,0u}}};

    // ---- h-phase: h @ W_hh^T, K = 512 in 8 plane-tiles, ping-pong buffers ----
    if (t > 0) {
        #pragma unroll
        for (int kt = 0; kt < 8; ++kt) {
            unsigned char*       wr = lds_mem + (kt & 1) * 40960;
            const unsigned char* rd = lds_mem + ((kt & 1) ^ 1) * 40960;
            if (kt < 7) {
                const size_t p1 = (size_t)(kt + 1) * E_N * 64;
                #pragma unroll
                for (int q = 0; q < 2; ++q)
                    GLDS16(hprev + p1 + (size_t)a_er[q] * 64 + a_sl2[q] * 8,
                           wr + (tid + q * 512) * 16);
                const int k1 = (kt + 1) * 64;
                #pragma unroll
                for (int q = 0; q < 3; ++q)
                    GLDS16(whh + (size_t)b_wr[q] * 512 + k1 + b_sl2[q] * 8,
                           wr + 16384 + (tid + q * 512) * 16);
            }
            if (kt == hold_kt) {
                // h_prev plane nb/64 lives in rd's A-region right now
                #pragma unroll
                for (int ni = 0; ni < 2; ++ni)
                    #pragma unroll
                    for (int mi = 0; mi < 2; ++mi)
                        #pragma unroll
                        for (int jp = 0; jp < 2; ++jp) {
                            int r0 = wm * 32 + mi * 16 + (lane >> 4) * 4 + jp * 2;
                            int r1 = r0 + 1;
                            int ac = (wn * 32 + ni * 16 + l15) * 2;
                            unsigned int lo = *(const unsigned short*)(rd + r0 * 128 + (ac ^ ((r0 & 7) << 4)));
                            unsigned int hi = *(const unsigned short*)(rd + r1 * 128 + (ac ^ ((r1 & 7) << 4)));
                            holdp[ni][mi][jp] = lo | (hi << 16);
                        }
            }
            mma_tile<3>(rd, acc, wm, wn, l15, hi8);
            wait_and_barrier();   // next buffer staged + all waves done with rd
        }
    }

    // ---- epilogue: gate math -> LDS out tile (reuse buf0.A) -> 16KB contiguous store ----
    unsigned char* lout = lds_mem;
    #pragma unroll
    for (int ni = 0; ni < 2; ++ni) {
        const int col = nb + wn * 32 + ni * 16 + l15;
        const float br0  = bih[col] + bhh[col];
        const float bz0  = bih[512 + col] + bhh[512 + col];
        const float bin_ = bih[1024 + col];
        const float bhn_ = bhh[1024 + col];
        #pragma unroll
        for (int mi = 0; mi < 2; ++mi) {
            #pragma unroll
            for (int j = 0; j < 4; ++j) {
                float r = fsig(acc[0][mi][ni][j] + br0);
                float z = fsig(acc[1][mi][ni][j] + bz0);
                float n = ftanhf(acc[2][mi][ni][j] + bin_ + r * (acc[3][mi][ni][j] + bhn_));
                float hold = (t > 0)
                    ? b2f((unsigned short)((holdp[ni][mi][j >> 1] >> ((j & 1) * 16)) & 0xffffu))
                    : 0.f;
                float hv = (1.f - z) * n + z * hold;
                int row = wm * 32 + mi * 16 + (lane >> 4) * 4 + j;
                int oc  = (wn * 32 + ni * 16 + l15) * 2;
                *(unsigned short*)(lout + row * 128 + (oc ^ ((row & 7) << 4))) = f2b(hv);
            }
        }
    }
    __syncthreads();
    const size_t oplane = (size_t)(nb >> 6) * E_N * 64;
    #pragma unroll
    for (int q = 0; q < 2; ++q) {
        int chunk = tid + q * 512;
        int row = chunk >> 3, c8 = chunk & 7;
        int grow = mb + row;
        if (grow < E_N) {
            uint4 v = *(const uint4*)(lout + row * 128 + ((c8 * 16) ^ ((row & 7) << 4)));
            *(uint4*)(hnext + oplane + (size_t)grow * 64 + c8 * 8) = v;
        }
    }
}

// ---------------------------------------------------------------------------
// attention logits + leaky relu. One wave per edge; 8-lane groups own a head.
// hl is blocked [8][E][64]; head h == plane h (64 cols each).
__global__ __launch_bounds__(256) void attn_logits(
    const unsigned short* __restrict__ hl, const float* __restrict__ attnw,
    float* __restrict__ a)
{
    int e = blockIdx.x * 4 + (threadIdx.x >> 6);
    int lane = threadIdx.x & 63;
    int h = lane >> 3;
    int c8 = lane & 7;
    uint4 v = *(const uint4*)(hl + (size_t)h * E_N * 64 + (size_t)e * 64 + c8 * 8);
    int dp = c8 * 8;
    float4 w0 = *(const float4*)(attnw + h * 64 + dp);
    float4 w1 = *(const float4*)(attnw + h * 64 + dp + 4);
    const unsigned short* u = (const unsigned short*)&v;
    float s = b2f(u[0]) * w0.x + b2f(u[1]) * w0.y + b2f(u[2]) * w0.z + b2f(u[3]) * w0.w
            + b2f(u[4]) * w1.x + b2f(u[5]) * w1.y + b2f(u[6]) * w1.z + b2f(u[7]) * w1.w;
    s += __shfl_xor(s, 1);
    s += __shfl_xor(s, 2);
    s += __shfl_xor(s, 4);
    if ((lane & 7) == 0)
        a[e * 8 + h] = s > 0.f ? s : 0.01f * s;
}

// per-dst edge lists (order within a list is arbitrary)
__global__ __launch_bounds__(256) void build_lists(
    const int* __restrict__ dstp, int* __restrict__ cnt, int* __restrict__ lists)
{
    int e = blockIdx.x * 256 + threadIdx.x;
    if (e < E_N) {
        int d = dstp[e];
        int slot = atomicAdd(&cnt[d], 1);
        if (slot < SLOTS) lists[(size_t)d * SLOTS + slot] = e;
    }
}

// One wave per dst: segment softmax + weighted gather-sum, plain stores.
// hl blocked [8][E][64]; lane's 8 cols sit in plane h = lane>>3.
__global__ __launch_bounds__(256) void aggregate(
    const unsigned short* __restrict__ hl, const float* __restrict__ a,
    const int* __restrict__ lists, const int* __restrict__ cnt,
    float* __restrict__ out)
{
    int d = blockIdx.x * 4 + (threadIdx.x >> 6);
    int lane = threadIdx.x & 63;
    int n = cnt[d];
    n = n < SLOTS ? n : SLOTS;
    const int h = lane >> 3;
    const int c8 = lane & 7;
    const int* lst = lists + (size_t)d * SLOTS;
    const unsigned short* plane = hl + (size_t)h * E_N * 64;

    float m = -1e30f;
    for (int i = 0; i < n; ++i)
        m = fmaxf(m, a[lst[i] * 8 + h]);
    float s = 0.f;
    for (int i = 0; i < n; ++i)
        s += __expf(a[lst[i] * 8 + h] - m);
    float rs = frcp(s);

    float acc[8] = {0.f, 0.f, 0.f, 0.f, 0.f, 0.f, 0.f, 0.f};
    for (int i = 0; i < n; ++i) {
        int e = lst[i];
        float alpha = __expf(a[e * 8 + h] - m) * rs;
        uint4 v = *(const uint4*)(plane + (size_t)e * 64 + c8 * 8);
        const unsigned short* u = (const unsigned short*)&v;
        #pragma unroll
        for (int j = 0; j < 8; ++j)
            acc[j] += alpha * b2f(u[j]);
    }
    float4 o0 = {acc[0], acc[1], acc[2], acc[3]};
    float4 o1 = {acc[4], acc[5], acc[6], acc[7]};
    float* op = out + (size_t)d * 512 + lane * 8;
    *(float4*)op = o0;
    *(float4*)(op + 4) = o1;
}

// ---------------------------------------------------------------------------
extern "C" void kernel_launch(void* const* d_in, const int* in_sizes, int n_in,
                              void* d_out, int out_size, void* d_ws, size_t ws_size,
                              hipStream_t stream)
{
    const float* features = (const float*)d_in[0];
    const float* W_ih     = (const float*)d_in[1];
    const float* W_hh     = (const float*)d_in[2];
    const float* b_ih     = (const float*)d_in[3];
    const float* b_hh     = (const float*)d_in[4];
    const float* attnw    = (const float*)d_in[5];
    const int*   emi      = (const int*)d_in[6];
    const int*   dstp     = (const int*)d_in[7];

    char* ws = (char*)d_ws;
    size_t off = 0;
    auto alloc = [&](size_t bytes) -> void* {
        void* p = ws + off;
        off = (off + bytes + 255) & ~(size_t)255;
        return p;
    };
    unsigned short* feat16 = (unsigned short*)alloc((size_t)NN_N * 64 * 2);
    unsigned short* wih16  = (unsigned short*)alloc((size_t)1536 * 64 * 2);
    unsigned short* whh16  = (unsigned short*)alloc((size_t)1536 * 512 * 2);
    unsigned short* h0     = (unsigned short*)alloc((size_t)E_N * 512 * 2);   // blocked [8][E][64]
    unsigned short* h1     = (unsigned short*)alloc((size_t)E_N * 512 * 2);   // blocked [8][E][64]
    float*          abuf   = (float*)alloc((size_t)E_N * 8 * 4);
    int*            cnt    = (int*)alloc((size_t)ND_N * 4);
    int*            lists  = (int*)alloc((size_t)ND_N * SLOTS * 4);

    conv_f2b<<<(NN_N * 64 / 4 + 255) / 256, 256, 0, stream>>>(features, feat16, NN_N * 64 / 4);
    conv_f2b<<<(1536 * 64 / 4 + 255) / 256, 256, 0, stream>>>(W_ih, wih16, 1536 * 64 / 4);
    conv_f2b<<<(1536 * 512 / 4 + 255) / 256, 256, 0, stream>>>(W_hh, whh16, 1536 * 512 / 4);

    zero_u4<<<(ND_N / 4 + 255) / 256, 256, 0, stream>>>((uint4*)cnt, ND_N / 4);

    // GRU: 3 steps; grid = 782 m-tiles x 8 n-tiles = 6256 (divisible by 8)
    const int grid = ((E_N + 127) / 128) * 8;
    gru_step<<<grid, 512, 0, stream>>>(feat16, emi, nullptr, h0, wih16, whh16, b_ih, b_hh, 0);
    gru_step<<<grid, 512, 0, stream>>>(feat16, emi, h0, h1, wih16, whh16, b_ih, b_hh, 1);
    gru_step<<<grid, 512, 0, stream>>>(feat16, emi, h1, h0, wih16, whh16, b_ih, b_hh, 2);

    // attention + dst-gather softmax/aggregation (no output atomics)
    attn_logits<<<E_N / 4, 256, 0, stream>>>(h0, attnw, abuf);
    build_lists<<<(E_N + 255) / 256, 256, 0, stream>>>(dstp, cnt, lists);
    aggregate<<<ND_N / 4, 256, 0, stream>>>(h0, abuf, lists, cnt, (float*)d_out);
}